// Round 16
// baseline (2509.514 us; speedup 1.0000x reference)
//
#include <hip/hip_runtime.h>
#include <hip/hip_bf16.h>

typedef __attribute__((ext_vector_type(8))) short bf16x8;
typedef __attribute__((ext_vector_type(4))) float f32x4;
typedef __attribute__((ext_vector_type(2))) int int32x2;

constexpr int kB = 64;      // batch
constexpr int kT = 512;     // time steps
constexpr int kE = 256;     // embedding
constexpr int kH = 512;     // hidden
constexpr int kV = 32000;   // vocab
constexpr int kBH = kB * kH;
constexpr int FSTR = 16;    // flag stride (ints) = 64B padding

static __device__ __forceinline__ unsigned short f2bf(float x) {
  __hip_bfloat16 h = __float2bfloat16(x);
  return __builtin_bit_cast(unsigned short, h);
}

static __device__ __forceinline__ f32x4 mfma16(bf16x8 a, bf16x8 b, f32x4 c) {
  return __builtin_amdgcn_mfma_f32_16x16x32_bf16(a, b, c, 0, 0, 0);
}

// issue 16 dwordx4 sc1 loads (64B stride), NO wait — overlap with compute.
static __device__ __forceinline__ void issue16_sc1(const unsigned short* p, bf16x8* a) {
  asm volatile(
      "global_load_dwordx4 %0, %16, off sc1\n\t"
      "global_load_dwordx4 %1, %16, off offset:64 sc1\n\t"
      "global_load_dwordx4 %2, %16, off offset:128 sc1\n\t"
      "global_load_dwordx4 %3, %16, off offset:192 sc1\n\t"
      "global_load_dwordx4 %4, %16, off offset:256 sc1\n\t"
      "global_load_dwordx4 %5, %16, off offset:320 sc1\n\t"
      "global_load_dwordx4 %6, %16, off offset:384 sc1\n\t"
      "global_load_dwordx4 %7, %16, off offset:448 sc1\n\t"
      "global_load_dwordx4 %8, %16, off offset:512 sc1\n\t"
      "global_load_dwordx4 %9, %16, off offset:576 sc1\n\t"
      "global_load_dwordx4 %10, %16, off offset:640 sc1\n\t"
      "global_load_dwordx4 %11, %16, off offset:704 sc1\n\t"
      "global_load_dwordx4 %12, %16, off offset:768 sc1\n\t"
      "global_load_dwordx4 %13, %16, off offset:832 sc1\n\t"
      "global_load_dwordx4 %14, %16, off offset:896 sc1\n\t"
      "global_load_dwordx4 %15, %16, off offset:960 sc1"
      : "=&v"(a[0]), "=&v"(a[1]), "=&v"(a[2]), "=&v"(a[3]),
        "=&v"(a[4]), "=&v"(a[5]), "=&v"(a[6]), "=&v"(a[7]),
        "=&v"(a[8]), "=&v"(a[9]), "=&v"(a[10]), "=&v"(a[11]),
        "=&v"(a[12]), "=&v"(a[13]), "=&v"(a[14]), "=&v"(a[15])
      : "v"(p));
}

// tied waits on 4 frags with various residual counts (straight-line use only;
// NEVER carry asm-load dests across a loop backedge — R15 NaN lesson)
#define WAIT4(NAME, CNT)                                                    \
  static __device__ __forceinline__ void NAME(bf16x8* a) {                  \
    asm volatile("s_waitcnt vmcnt(" #CNT ")"                                \
                 : "+v"(a[0]), "+v"(a[1]), "+v"(a[2]), "+v"(a[3])           \
                 :                                                          \
                 : "memory");                                               \
  }
WAIT4(wait4_vm12, 12)
WAIT4(wait4_vm8, 8)
WAIT4(wait4_vm4, 4)
WAIT4(wait4_vm0, 0)
#undef WAIT4

#define WAIT8(NAME, CNT)                                                    \
  static __device__ __forceinline__ void NAME(bf16x8* a) {                  \
    asm volatile("s_waitcnt vmcnt(" #CNT ")"                                \
                 : "+v"(a[0]), "+v"(a[1]), "+v"(a[2]), "+v"(a[3]),          \
                   "+v"(a[4]), "+v"(a[5]), "+v"(a[6]), "+v"(a[7])           \
                 :                                                          \
                 : "memory");                                               \
  }
WAIT8(wait8_vm24, 24)
WAIT8(wait8_vm16, 16)
WAIT8(wait8_vm8, 8)
WAIT8(wait8_vm0, 0)
#undef WAIT8

static __device__ __forceinline__ void store_dwordx2_sc1(unsigned short* p, int32x2 v) {
  asm volatile("global_store_dwordx2 %0, %1, off sc1" ::"v"(p), "v"(v) : "memory");
}

static __device__ __forceinline__ void store_int_sc1(int* p, int v) {
  asm volatile("global_store_dword %0, %1, off sc1" ::"v"(p), "v"(v) : "memory");
}

// spin until (per-lane) *p >= thr for all 64 lanes; 1 dword sc1 load/lane/iter.
static __device__ __forceinline__ void pollgate(const int* p, int thr) {
  while (true) {
    int v;
    asm volatile("global_load_dword %0, %1, off sc1\n\ts_waitcnt vmcnt(0)"
                 : "=&v"(v)
                 : "v"(p)
                 : "memory");
    if (__all(v >= thr)) break;
  }
}

// Pack weights into A-fragment slices: P[hb][kc][gate][lane][j]
//   = src_gate[(kc*32 + (lane>>4)*8 + j) * kH + hb*16 + (lane&15)]
// blockIdx.y selects which of the 4 packed matrices (fused single launch).
__global__ void pack_all(const float* __restrict__ U_f, const float* __restrict__ U_i,
                         const float* __restrict__ U_g, const float* __restrict__ U_o,
                         const float* __restrict__ V_f, const float* __restrict__ V_i,
                         const float* __restrict__ V_g, const float* __restrict__ V_o1,
                         const float* __restrict__ U_f1, const float* __restrict__ U_i1,
                         const float* __restrict__ U_g1, const float* __restrict__ U_o1,
                         const float* __restrict__ V_f1, const float* __restrict__ V_i1,
                         const float* __restrict__ V_g1,
                         unsigned short* __restrict__ U0p, unsigned short* __restrict__ V0p,
                         unsigned short* __restrict__ U1p, unsigned short* __restrict__ V1p) {
  const int which = blockIdx.y;
  const float *s0, *s1, *s2, *s3;
  unsigned short* dst;
  int K;
  if (which == 0)      { s0 = U_f;  s1 = U_i;  s2 = U_g;  s3 = U_o;  dst = U0p; K = kE; }
  else if (which == 1) { s0 = V_f;  s1 = V_i;  s2 = V_g;  s3 = V_o1; dst = V0p; K = kH; }
  else if (which == 2) { s0 = U_f1; s1 = U_i1; s2 = U_g1; s3 = U_o1; dst = U1p; K = kH; }
  else                 { s0 = V_f1; s1 = V_i1; s2 = V_g1; s3 = V_o1; dst = V1p; K = kH; }
  int o = blockIdx.x * 256 + threadIdx.x;
  if (o >= K * 2048) return;
  int j = o & 7;
  int lane = (o >> 3) & 63;
  int gate = (o >> 9) & 3;
  int r2 = o >> 11;
  int kc = r2 % (K / 32);
  int hb = r2 / (K / 32);
  int k = kc * 32 + (lane >> 4) * 8 + j;
  int hid = hb * 16 + (lane & 15);
  const float* s = (gate == 0) ? s0 : (gate == 1) ? s1 : (gate == 2) ? s2 : s3;
  dst[o] = f2bf(s[(size_t)k * kH + hid]);
}

// xseq[t][b][e] = bf16(emb[X[b][t]][e])
__global__ void gather_x(const int* __restrict__ X, const float* __restrict__ emb,
                         unsigned short* __restrict__ xseq) {
  int o = blockIdx.x * 256 + threadIdx.x;
  if (o >= kT * kB * (kE / 8)) return;
  int e8 = o & 31;
  int b = (o >> 5) & 63;
  int t = o >> 11;
  int tok = X[b * kT + t];
  const float* src = emb + (size_t)tok * kE + e8 * 8;
  unsigned short tmp[8];
#pragma unroll
  for (int j = 0; j < 8; ++j) tmp[j] = f2bf(src[j]);
  unsigned short* dst = xseq + ((size_t)t * kB + b) * kE + e8 * 8;
#pragma unroll
  for (int j = 0; j < 8; ++j) dst[j] = tmp[j];
}

// init states to ones; planar bias arrays [4][512]; zero flags
__global__ void init_state(unsigned short* hbuf, unsigned short* h1buf,
                           float* bcat0, float* bcat1, int* fl0, int* fl1,
                           const float* b_f, const float* b_i, const float* b_g,
                           const float* b_o1,
                           const float* b_f1, const float* b_i1, const float* b_g1) {
  int i = blockIdx.x * 256 + threadIdx.x;
  if (i < 8 * kBH) hbuf[i] = 0x3F80u;  // bf16 1.0
  if (i < 2 * kBH) h1buf[i] = 0x3F80u;
  if (i < 512) {
    bcat0[i] = b_f[i];  bcat0[512 + i] = b_i[i];
    bcat0[1024 + i] = b_g[i];  bcat0[1536 + i] = b_o1[i];
    bcat1[i] = b_f1[i]; bcat1[512 + i] = b_i1[i];
    bcat1[1024 + i] = b_g1[i]; bcat1[1536 + i] = b_o1[i];
  }
  if (i < 4 * 32 * FSTR) { fl0[i] = 0; fl1[i] = 0; }
}

// Persistent recurrence: 256 WGs x 64 threads (1 wave each, 1 per CU).
// WGs [0,128): layer0 (h).  WGs [128,256): layer1 (h1).
// wl = wg&127; hb = wl>>2 (hidden block), bt = wl&3 (batch group of 16).
// Point-to-point flags along true dependencies, per bt-group (R6-proven):
//   L0 step t: fl0[bt][*] >= t (vF = h(t-1)); fl1[bt][*] >= t-7 (slot reuse)
//   L1 step s: fl0[bt][*] >= s+1 (uF = h(s)); fl1[bt][*] >= s (vF = h1(s-1))
// R16: finer counted-vmcnt splits (4-chunk) within each iteration; all asm
// load dests consumed straight-line (no backedge carry — R15 NaN lesson).
__global__ void __launch_bounds__(64, 1)
lstm_rec(const unsigned short* __restrict__ xseq,
         const unsigned short* __restrict__ U0p, const unsigned short* __restrict__ V0p,
         const unsigned short* __restrict__ U1p, const unsigned short* __restrict__ V1p,
         const float* __restrict__ bcat0, const float* __restrict__ bcat1,
         unsigned short* __restrict__ hbuf,   // [8][64][512] bf16
         unsigned short* __restrict__ h1buf,  // [2][64][512] bf16
         float* __restrict__ h1f,             // [64][512] fp32 final h1
         int* __restrict__ fl0,               // [4][32*FSTR] L0 flags
         int* __restrict__ fl1)               // [4][32*FSTR] L1 flags
{
  extern __shared__ unsigned short lds[];
  const int lane = threadIdx.x;
  const int wg = blockIdx.x;
  const bool isL1 = wg >= 128;
  const int wl = wg & 127;
  const int hb = wl >> 2, bt = wl & 3;
  const int l15 = lane & 15, g4 = lane >> 4;
  const int batch = bt * 16 + l15;
  const int hid4 = hb * 16 + g4 * 4;
  const int KU = isL1 ? 512 : 256;

  // stage this WG's weight slice (A-fragment layout) into LDS, once
  {
    const unsigned short* Wu = isL1 ? U1p : U0p;
    const unsigned short* Wv = isL1 ? V1p : V0p;
    const int nu = KU * 64, nv = 512 * 64;
    const bf16x8* su = (const bf16x8*)(Wu + (size_t)hb * nu);
    bf16x8* d = (bf16x8*)lds;
    for (int i = lane; i < nu / 8; i += 64) d[i] = su[i];
    const bf16x8* sv = (const bf16x8*)(Wv + (size_t)hb * nv);
    bf16x8* d2 = (bf16x8*)(lds + nu);
    for (int i = lane; i < nv / 8; i += 64) d2[i] = sv[i];
  }

  // per-lane poll pointer + threshold offset (thr = step - off)
  const int* pollp = (lane < 32) ? (fl0 + bt * 32 * FSTR + lane * FSTR)
                                 : (fl1 + bt * 32 * FSTR + (lane - 32) * FSTR);
  const int throff = isL1 ? (lane < 32 ? -1 : 0) : (lane < 32 ? 0 : 7);
  int* myflag = (isL1 ? fl1 : fl0) + bt * 32 * FSTR + hb * FSTR;

  const float* bc = isL1 ? bcat1 : bcat0;
  const float4 bF = *(const float4*)(bc + 0 * 512 + hid4);
  const float4 bI = *(const float4*)(bc + 1 * 512 + hid4);
  const float4 bG = *(const float4*)(bc + 2 * 512 + hid4);
  const float4 bO = *(const float4*)(bc + 3 * 512 + hid4);
  float cst[4] = {1.f, 1.f, 1.f, 1.f};

#define MFMA_KC(BASE_KC, FRAG)                                               \
  {                                                                          \
    const unsigned short* ab = lds + (BASE_KC) * 2048 + lane * 8;            \
    acc[0] = mfma16(*(const bf16x8*)ab, FRAG, acc[0]);                       \
    acc[1] = mfma16(*(const bf16x8*)(ab + 512), FRAG, acc[1]);               \
    acc[2] = mfma16(*(const bf16x8*)(ab + 1024), FRAG, acc[2]);              \
    acc[3] = mfma16(*(const bf16x8*)(ab + 1536), FRAG, acc[3]);              \
  }

#define GATE_EPILOGUE(hv)                                                      \
  float hv[4];                                                                 \
  {                                                                            \
    const float bfv[4] = {bF.x, bF.y, bF.z, bF.w};                             \
    const float biv[4] = {bI.x, bI.y, bI.z, bI.w};                             \
    const float bgv[4] = {bG.x, bG.y, bG.z, bG.w};                             \
    const float bov[4] = {bO.x, bO.y, bO.z, bO.w};                             \
    _Pragma("unroll") for (int r = 0; r < 4; ++r) {                            \
      float fg = 1.f / (1.f + __expf(-(acc[0][r] + bfv[r])));                  \
      float ig = 1.f / (1.f + __expf(-(acc[1][r] + biv[r])));                  \
      float e2 = __expf(2.f * (acc[2][r] + bgv[r]));                           \
      float gg = (e2 - 1.f) / (e2 + 1.f);                                      \
      float og = 1.f / (1.f + __expf(-(acc[3][r] + bov[r])));                  \
      float cn = fg * cst[r] + ig * gg;                                        \
      cst[r] = cn;                                                             \
      float e2c = __expf(2.f * cn);                                            \
      hv[r] = og * (e2c - 1.f) / (e2c + 1.f);                                  \
    }                                                                          \
  }

  if (!isL1) {
    // ================= layer 0 =================
    bf16x8 xr[8];
    {
      const unsigned short* xp = xseq + (size_t)batch * kE + g4 * 8;  // t=0
#pragma unroll
      for (int kc = 0; kc < 8; ++kc) xr[kc] = *(const bf16x8*)(xp + kc * 32);
    }
    for (int t = 0; t < kT; ++t) {
      pollgate(pollp, t - throff);  // also drains xr prefetch (vmcnt 0)
      bf16x8 vF[16];
      issue16_sc1(hbuf + (size_t)((t + 7) & 7) * kBH + batch * kH + g4 * 8, vF);
      f32x4 acc[4] = {{0, 0, 0, 0}, {0, 0, 0, 0}, {0, 0, 0, 0}, {0, 0, 0, 0}};
#pragma unroll
      for (int kc = 0; kc < 8; ++kc) MFMA_KC(kc, xr[kc])  // U-part; vF in flight
      wait4_vm12(vF);
#pragma unroll
      for (int kc = 0; kc < 4; ++kc) MFMA_KC(8 + kc, vF[kc])
      wait4_vm8(vF + 4);
#pragma unroll
      for (int kc = 4; kc < 8; ++kc) MFMA_KC(8 + kc, vF[kc])
      wait4_vm4(vF + 8);
#pragma unroll
      for (int kc = 8; kc < 12; ++kc) MFMA_KC(8 + kc, vF[kc])
      wait4_vm0(vF + 12);
#pragma unroll
      for (int kc = 12; kc < 16; ++kc) MFMA_KC(8 + kc, vF[kc])
      GATE_EPILOGUE(hv)
      unsigned int lo = (unsigned)f2bf(hv[0]) | ((unsigned)f2bf(hv[1]) << 16);
      unsigned int hi = (unsigned)f2bf(hv[2]) | ((unsigned)f2bf(hv[3]) << 16);
      int32x2 pk = {(int)lo, (int)hi};
      store_dwordx2_sc1(hbuf + (size_t)(t & 7) * kBH + batch * kH + hid4, pk);
      if (t + 1 < kT) {  // prefetch next x; stays in flight across flag store
        const unsigned short* xp =
            xseq + ((size_t)(t + 1) * kB + batch) * kE + g4 * 8;
#pragma unroll
        for (int kc = 0; kc < 8; ++kc) xr[kc] = *(const bf16x8*)(xp + kc * 32);
        asm volatile("s_waitcnt vmcnt(8)" ::: "memory");  // h-store acked only
      } else {
        asm volatile("s_waitcnt vmcnt(0)" ::: "memory");
      }
      if (lane == 0) store_int_sc1(myflag, t + 1);
    }
  } else {
    // ================= layer 1 =================
    for (int s = 0; s < kT; ++s) {
      pollgate(pollp, s - throff);
      bf16x8 uF[16], vF[16];
      issue16_sc1(hbuf + (size_t)(s & 7) * kBH + batch * kH + g4 * 8, uF);
      issue16_sc1(h1buf + (size_t)((s + 1) & 1) * kBH + batch * kH + g4 * 8, vF);
      f32x4 acc[4] = {{0, 0, 0, 0}, {0, 0, 0, 0}, {0, 0, 0, 0}, {0, 0, 0, 0}};
      wait8_vm24(uF);       // oldest 8 (uF[0..7]) complete
#pragma unroll
      for (int kc = 0; kc < 8; ++kc) MFMA_KC(kc, uF[kc])
      wait8_vm16(uF + 8);   // uF[8..15]
#pragma unroll
      for (int kc = 8; kc < 16; ++kc) MFMA_KC(kc, uF[kc])
      wait8_vm8(vF);        // vF[0..7]
#pragma unroll
      for (int kc = 0; kc < 8; ++kc) MFMA_KC(16 + kc, vF[kc])
      wait8_vm0(vF + 8);    // vF[8..15]
#pragma unroll
      for (int kc = 8; kc < 16; ++kc) MFMA_KC(16 + kc, vF[kc])
      GATE_EPILOGUE(hv)
      if (s == kT - 1) {
        f32x4 hq = {hv[0], hv[1], hv[2], hv[3]};
        *(f32x4*)(h1f + (size_t)batch * kH + hid4) = hq;  // kernel-end flush
      } else {
        unsigned int lo = (unsigned)f2bf(hv[0]) | ((unsigned)f2bf(hv[1]) << 16);
        unsigned int hi = (unsigned)f2bf(hv[2]) | ((unsigned)f2bf(hv[3]) << 16);
        int32x2 pk = {(int)lo, (int)hi};
        store_dwordx2_sc1(h1buf + (size_t)(s & 1) * kBH + batch * kH + hid4, pk);
      }
      asm volatile("s_waitcnt vmcnt(0)" ::: "memory");
      if (lane == 0) store_int_sc1(myflag, s + 1);
    }
  }
#undef GATE_EPILOGUE
#undef MFMA_KC
}

// out[b][v] = 2*sum_k h1[b][k]*Wout[k][v] + bout[v]; ALL 64 batches per block
// (single pass over W_out: halves HBM traffic vs two batch-halves)
__global__ void head(const float* __restrict__ h1f, const float* __restrict__ Wout,
                     const float* __restrict__ bout, float* __restrict__ out) {
  extern __shared__ float hs[];  // [64][512] = 128KB dynamic LDS
  const int v = blockIdx.x * 256 + threadIdx.x;
  for (int i = threadIdx.x; i < 64 * kH / 4; i += 256)
    ((float4*)hs)[i] = ((const float4*)h1f)[i];
  __syncthreads();
  float acc[64];
#pragma unroll
  for (int r = 0; r < 64; ++r) acc[r] = 0.f;
  for (int k = 0; k < kH; k += 4) {
    float w0 = Wout[(size_t)k * kV + v];
    float w1 = Wout[(size_t)(k + 1) * kV + v];
    float w2 = Wout[(size_t)(k + 2) * kV + v];
    float w3 = Wout[(size_t)(k + 3) * kV + v];
#pragma unroll
    for (int r = 0; r < 64; ++r) {
      float4 h4 = *(const float4*)&hs[r * kH + k];  // LDS broadcast
      acc[r] += h4.x * w0 + h4.y * w1 + h4.z * w2 + h4.w * w3;
    }
  }
  float bv = bout[v];
#pragma unroll
  for (int r = 0; r < 64; ++r)
    out[(size_t)r * kV + v] = 2.f * acc[r] + bv;
}

extern "C" void kernel_launch(void* const* d_in, const int* in_sizes, int n_in,
                              void* d_out, int out_size, void* d_ws, size_t ws_size,
                              hipStream_t stream) {
  const int*   X     = (const int*)d_in[0];
  const float* emb   = (const float*)d_in[1];
  const float* U_f   = (const float*)d_in[2];
  const float* V_f   = (const float*)d_in[3];
  const float* b_f   = (const float*)d_in[4];
  const float* U_i   = (const float*)d_in[5];
  const float* V_i   = (const float*)d_in[6];
  const float* b_i   = (const float*)d_in[7];
  const float* U_g   = (const float*)d_in[8];
  const float* V_g   = (const float*)d_in[9];
  const float* b_g   = (const float*)d_in[10];
  const float* U_o   = (const float*)d_in[11];
  const float* U_f1  = (const float*)d_in[12];
  const float* V_f1  = (const float*)d_in[13];
  const float* b_f1  = (const float*)d_in[14];
  const float* U_i1  = (const float*)d_in[15];
  const float* V_i1  = (const float*)d_in[16];
  const float* b_i1  = (const float*)d_in[17];
  const float* U_g1  = (const float*)d_in[18];
  const float* V_g1  = (const float*)d_in[19];
  const float* b_g1  = (const float*)d_in[20];
  const float* U_o1  = (const float*)d_in[21];
  const float* V_o1  = (const float*)d_in[22];
  const float* b_o1  = (const float*)d_in[23];
  const float* W_out = (const float*)d_in[24];
  const float* b_out = (const float*)d_in[25];

  char* ws = (char*)d_ws;
  auto alloc = [&](size_t bytes) -> char* {
    char* p = ws;
    ws += (bytes + 255) & ~(size_t)255;
    return p;
  };
  unsigned short* U0p   = (unsigned short*)alloc((size_t)kE * 2048 * 2);
  unsigned short* V0p   = (unsigned short*)alloc((size_t)kH * 2048 * 2);
  unsigned short* U1p   = (unsigned short*)alloc((size_t)kH * 2048 * 2);
  unsigned short* V1p   = (unsigned short*)alloc((size_t)kH * 2048 * 2);
  unsigned short* xseq  = (unsigned short*)alloc((size_t)kT * kB * kE * 2);
  unsigned short* hbuf  = (unsigned short*)alloc((size_t)8 * kBH * 2);
  unsigned short* h1buf = (unsigned short*)alloc((size_t)2 * kBH * 2);
  float* h1f   = (float*)alloc((size_t)kBH * 4);
  float* bcat0 = (float*)alloc(4 * 512 * 4);
  float* bcat1 = (float*)alloc(4 * 512 * 4);
  int* fl0     = (int*)alloc(4 * 32 * FSTR * 4);
  int* fl1     = (int*)alloc(4 * 32 * FSTR * 4);

  // fused weight packing (layer0 o-gate uses V_o1 and b_o1 — reference quirk)
  pack_all<<<dim3((kH * 2048 + 255) / 256, 4), 256, 0, stream>>>(
      U_f, U_i, U_g, U_o, V_f, V_i, V_g, V_o1,
      U_f1, U_i1, U_g1, U_o1, V_f1, V_i1, V_g1,
      U0p, V0p, U1p, V1p);
  gather_x<<<(kT * kB * (kE / 8) + 255) / 256, 256, 0, stream>>>(X, emb, xseq);
  init_state<<<(8 * kBH + 255) / 256, 256, 0, stream>>>(
      hbuf, h1buf, bcat0, bcat1, fl0, fl1,
      b_f, b_i, b_g, b_o1, b_f1, b_i1, b_g1);

  (void)hipFuncSetAttribute((const void*)lstm_rec,
                            hipFuncAttributeMaxDynamicSharedMemorySize, 131072);
  void* args[] = {
      (void*)&xseq, (void*)&U0p, (void*)&V0p, (void*)&U1p, (void*)&V1p,
      (void*)&bcat0, (void*)&bcat1, (void*)&hbuf, (void*)&h1buf,
      (void*)&h1f, (void*)&fl0, (void*)&fl1};
  (void)hipLaunchCooperativeKernel((const void*)lstm_rec, dim3(256), dim3(64),
                                   args, 131072, stream);

  (void)hipFuncSetAttribute((const void*)head,
                            hipFuncAttributeMaxDynamicSharedMemorySize, 131072);
  head<<<dim3(kV / 256, 1), 256, 131072, stream>>>(h1f, W_out, b_out,
                                                   (float*)d_out);
}

// Round 17
// 2370.971 us; speedup vs baseline: 1.0584x; 1.0584x over previous
//
#include <hip/hip_runtime.h>
#include <hip/hip_bf16.h>

typedef __attribute__((ext_vector_type(8))) short bf16x8;
typedef __attribute__((ext_vector_type(4))) float f32x4;
typedef __attribute__((ext_vector_type(2))) int int32x2;

constexpr int kB = 64;      // batch
constexpr int kT = 512;     // time steps
constexpr int kE = 256;     // embedding
constexpr int kH = 512;     // hidden
constexpr int kV = 32000;   // vocab
constexpr int kBH = kB * kH;
constexpr int FSTR = 16;    // flag stride (ints) = 64B padding

static __device__ __forceinline__ unsigned short f2bf(float x) {
  __hip_bfloat16 h = __float2bfloat16(x);
  return __builtin_bit_cast(unsigned short, h);
}

static __device__ __forceinline__ f32x4 mfma16(bf16x8 a, bf16x8 b, f32x4 c) {
  return __builtin_amdgcn_mfma_f32_16x16x32_bf16(a, b, c, 0, 0, 0);
}

// issue 16 dwordx4 sc1 loads (64B stride), NO wait — overlap with compute.
static __device__ __forceinline__ void issue16_sc1(const unsigned short* p, bf16x8* a) {
  asm volatile(
      "global_load_dwordx4 %0, %16, off sc1\n\t"
      "global_load_dwordx4 %1, %16, off offset:64 sc1\n\t"
      "global_load_dwordx4 %2, %16, off offset:128 sc1\n\t"
      "global_load_dwordx4 %3, %16, off offset:192 sc1\n\t"
      "global_load_dwordx4 %4, %16, off offset:256 sc1\n\t"
      "global_load_dwordx4 %5, %16, off offset:320 sc1\n\t"
      "global_load_dwordx4 %6, %16, off offset:384 sc1\n\t"
      "global_load_dwordx4 %7, %16, off offset:448 sc1\n\t"
      "global_load_dwordx4 %8, %16, off offset:512 sc1\n\t"
      "global_load_dwordx4 %9, %16, off offset:576 sc1\n\t"
      "global_load_dwordx4 %10, %16, off offset:640 sc1\n\t"
      "global_load_dwordx4 %11, %16, off offset:704 sc1\n\t"
      "global_load_dwordx4 %12, %16, off offset:768 sc1\n\t"
      "global_load_dwordx4 %13, %16, off offset:832 sc1\n\t"
      "global_load_dwordx4 %14, %16, off offset:896 sc1\n\t"
      "global_load_dwordx4 %15, %16, off offset:960 sc1"
      : "=&v"(a[0]), "=&v"(a[1]), "=&v"(a[2]), "=&v"(a[3]),
        "=&v"(a[4]), "=&v"(a[5]), "=&v"(a[6]), "=&v"(a[7]),
        "=&v"(a[8]), "=&v"(a[9]), "=&v"(a[10]), "=&v"(a[11]),
        "=&v"(a[12]), "=&v"(a[13]), "=&v"(a[14]), "=&v"(a[15])
      : "v"(p));
}

// tied waits on 4 frags with various residual counts (straight-line use only;
// NEVER carry asm-load dests across a loop backedge — R15 NaN lesson)
#define WAIT4(NAME, CNT)                                                    \
  static __device__ __forceinline__ void NAME(bf16x8* a) {                  \
    asm volatile("s_waitcnt vmcnt(" #CNT ")"                                \
                 : "+v"(a[0]), "+v"(a[1]), "+v"(a[2]), "+v"(a[3])           \
                 :                                                          \
                 : "memory");                                               \
  }
WAIT4(wait4_vm12, 12)
WAIT4(wait4_vm8, 8)
WAIT4(wait4_vm4, 4)
WAIT4(wait4_vm0, 0)
#undef WAIT4

#define WAIT8(NAME, CNT)                                                    \
  static __device__ __forceinline__ void NAME(bf16x8* a) {                  \
    asm volatile("s_waitcnt vmcnt(" #CNT ")"                                \
                 : "+v"(a[0]), "+v"(a[1]), "+v"(a[2]), "+v"(a[3]),          \
                   "+v"(a[4]), "+v"(a[5]), "+v"(a[6]), "+v"(a[7])           \
                 :                                                          \
                 : "memory");                                               \
  }
WAIT8(wait8_vm24, 24)
WAIT8(wait8_vm16, 16)
WAIT8(wait8_vm8, 8)
WAIT8(wait8_vm0, 0)
#undef WAIT8

static __device__ __forceinline__ void store_dwordx2_sc1(unsigned short* p, int32x2 v) {
  asm volatile("global_store_dwordx2 %0, %1, off sc1" ::"v"(p), "v"(v) : "memory");
}

static __device__ __forceinline__ void store_int_sc1(int* p, int v) {
  asm volatile("global_store_dword %0, %1, off sc1" ::"v"(p), "v"(v) : "memory");
}

// spin until (per-lane) *p >= thr for all 64 lanes; 1 dword sc1 load/lane/iter.
static __device__ __forceinline__ void pollgate(const int* p, int thr) {
  while (true) {
    int v;
    asm volatile("global_load_dword %0, %1, off sc1\n\ts_waitcnt vmcnt(0)"
                 : "=&v"(v)
                 : "v"(p)
                 : "memory");
    if (__all(v >= thr)) break;
  }
}

// Pack weights into A-fragment slices: P[hb][kc][gate][lane][j]
//   = src_gate[(kc*32 + (lane>>4)*8 + j) * kH + hb*16 + (lane&15)]
// blockIdx.y selects which of the 4 packed matrices (fused single launch).
__global__ void pack_all(const float* __restrict__ U_f, const float* __restrict__ U_i,
                         const float* __restrict__ U_g, const float* __restrict__ U_o,
                         const float* __restrict__ V_f, const float* __restrict__ V_i,
                         const float* __restrict__ V_g, const float* __restrict__ V_o1,
                         const float* __restrict__ U_f1, const float* __restrict__ U_i1,
                         const float* __restrict__ U_g1, const float* __restrict__ U_o1,
                         const float* __restrict__ V_f1, const float* __restrict__ V_i1,
                         const float* __restrict__ V_g1,
                         unsigned short* __restrict__ U0p, unsigned short* __restrict__ V0p,
                         unsigned short* __restrict__ U1p, unsigned short* __restrict__ V1p) {
  const int which = blockIdx.y;
  const float *s0, *s1, *s2, *s3;
  unsigned short* dst;
  int K;
  if (which == 0)      { s0 = U_f;  s1 = U_i;  s2 = U_g;  s3 = U_o;  dst = U0p; K = kE; }
  else if (which == 1) { s0 = V_f;  s1 = V_i;  s2 = V_g;  s3 = V_o1; dst = V0p; K = kH; }
  else if (which == 2) { s0 = U_f1; s1 = U_i1; s2 = U_g1; s3 = U_o1; dst = U1p; K = kH; }
  else                 { s0 = V_f1; s1 = V_i1; s2 = V_g1; s3 = V_o1; dst = V1p; K = kH; }
  int o = blockIdx.x * 256 + threadIdx.x;
  if (o >= K * 2048) return;
  int j = o & 7;
  int lane = (o >> 3) & 63;
  int gate = (o >> 9) & 3;
  int r2 = o >> 11;
  int kc = r2 % (K / 32);
  int hb = r2 / (K / 32);
  int k = kc * 32 + (lane >> 4) * 8 + j;
  int hid = hb * 16 + (lane & 15);
  const float* s = (gate == 0) ? s0 : (gate == 1) ? s1 : (gate == 2) ? s2 : s3;
  dst[o] = f2bf(s[(size_t)k * kH + hid]);
}

// xseq[t][b][e] = bf16(emb[X[b][t]][e])
__global__ void gather_x(const int* __restrict__ X, const float* __restrict__ emb,
                         unsigned short* __restrict__ xseq) {
  int o = blockIdx.x * 256 + threadIdx.x;
  if (o >= kT * kB * (kE / 8)) return;
  int e8 = o & 31;
  int b = (o >> 5) & 63;
  int t = o >> 11;
  int tok = X[b * kT + t];
  const float* src = emb + (size_t)tok * kE + e8 * 8;
  unsigned short tmp[8];
#pragma unroll
  for (int j = 0; j < 8; ++j) tmp[j] = f2bf(src[j]);
  unsigned short* dst = xseq + ((size_t)t * kB + b) * kE + e8 * 8;
#pragma unroll
  for (int j = 0; j < 8; ++j) dst[j] = tmp[j];
}

// init states to ones; planar bias arrays [4][512]; zero flags
__global__ void init_state(unsigned short* hbuf, unsigned short* h1buf,
                           float* bcat0, float* bcat1, int* fl0, int* fl1,
                           const float* b_f, const float* b_i, const float* b_g,
                           const float* b_o1,
                           const float* b_f1, const float* b_i1, const float* b_g1) {
  int i = blockIdx.x * 256 + threadIdx.x;
  if (i < 8 * kBH) hbuf[i] = 0x3F80u;  // bf16 1.0
  if (i < 2 * kBH) h1buf[i] = 0x3F80u;
  if (i < 512) {
    bcat0[i] = b_f[i];  bcat0[512 + i] = b_i[i];
    bcat0[1024 + i] = b_g[i];  bcat0[1536 + i] = b_o1[i];
    bcat1[i] = b_f1[i]; bcat1[512 + i] = b_i1[i];
    bcat1[1024 + i] = b_g1[i]; bcat1[1536 + i] = b_o1[i];
  }
  if (i < 4 * 32 * FSTR) { fl0[i] = 0; fl1[i] = 0; }
}

// Persistent recurrence: 256 WGs x 64 threads (1 wave each, 1 per CU).
// WGs [0,128): layer0 (h).  WGs [128,256): layer1 (h1).
// wl = wg&127; hb = wl>>2 (hidden block), bt = wl&3 (batch group of 16).
// Point-to-point flags along true dependencies, per bt-group (R6-proven):
//   L0 step t: fl0[bt][*] >= t (vF = h(t-1)); fl1[bt][*] >= t-7 (slot reuse)
//   L1 step s: fl0[bt][*] >= s+1 (uF = h(s)); fl1[bt][*] >= s (vF = h1(s-1))
// Finer counted-vmcnt splits within each iteration; all asm load dests
// consumed straight-line (no backedge carry — R15 NaN lesson).
__global__ void __launch_bounds__(64, 1)
lstm_rec(const unsigned short* __restrict__ xseq,
         const unsigned short* __restrict__ U0p, const unsigned short* __restrict__ V0p,
         const unsigned short* __restrict__ U1p, const unsigned short* __restrict__ V1p,
         const float* __restrict__ bcat0, const float* __restrict__ bcat1,
         unsigned short* __restrict__ hbuf,   // [8][64][512] bf16
         unsigned short* __restrict__ h1buf,  // [2][64][512] bf16
         float* __restrict__ h1f,             // [64][512] fp32 final h1
         int* __restrict__ fl0,               // [4][32*FSTR] L0 flags
         int* __restrict__ fl1)               // [4][32*FSTR] L1 flags
{
  extern __shared__ unsigned short lds[];
  const int lane = threadIdx.x;
  const int wg = blockIdx.x;
  const bool isL1 = wg >= 128;
  const int wl = wg & 127;
  const int hb = wl >> 2, bt = wl & 3;
  const int l15 = lane & 15, g4 = lane >> 4;
  const int batch = bt * 16 + l15;
  const int hid4 = hb * 16 + g4 * 4;
  const int KU = isL1 ? 512 : 256;

  // stage this WG's weight slice (A-fragment layout) into LDS, once
  {
    const unsigned short* Wu = isL1 ? U1p : U0p;
    const unsigned short* Wv = isL1 ? V1p : V0p;
    const int nu = KU * 64, nv = 512 * 64;
    const bf16x8* su = (const bf16x8*)(Wu + (size_t)hb * nu);
    bf16x8* d = (bf16x8*)lds;
    for (int i = lane; i < nu / 8; i += 64) d[i] = su[i];
    const bf16x8* sv = (const bf16x8*)(Wv + (size_t)hb * nv);
    bf16x8* d2 = (bf16x8*)(lds + nu);
    for (int i = lane; i < nv / 8; i += 64) d2[i] = sv[i];
  }

  // per-lane poll pointer + threshold offset (thr = step - off)
  const int* pollp = (lane < 32) ? (fl0 + bt * 32 * FSTR + lane * FSTR)
                                 : (fl1 + bt * 32 * FSTR + (lane - 32) * FSTR);
  const int throff = isL1 ? (lane < 32 ? -1 : 0) : (lane < 32 ? 0 : 7);
  int* myflag = (isL1 ? fl1 : fl0) + bt * 32 * FSTR + hb * FSTR;

  const float* bc = isL1 ? bcat1 : bcat0;
  const float4 bF = *(const float4*)(bc + 0 * 512 + hid4);
  const float4 bI = *(const float4*)(bc + 1 * 512 + hid4);
  const float4 bG = *(const float4*)(bc + 2 * 512 + hid4);
  const float4 bO = *(const float4*)(bc + 3 * 512 + hid4);
  float cst[4] = {1.f, 1.f, 1.f, 1.f};

#define MFMA_KC(BASE_KC, FRAG)                                               \
  {                                                                          \
    const unsigned short* ab = lds + (BASE_KC) * 2048 + lane * 8;            \
    acc[0] = mfma16(*(const bf16x8*)ab, FRAG, acc[0]);                       \
    acc[1] = mfma16(*(const bf16x8*)(ab + 512), FRAG, acc[1]);               \
    acc[2] = mfma16(*(const bf16x8*)(ab + 1024), FRAG, acc[2]);              \
    acc[3] = mfma16(*(const bf16x8*)(ab + 1536), FRAG, acc[3]);              \
  }

#define GATE_EPILOGUE(hv)                                                      \
  float hv[4];                                                                 \
  {                                                                            \
    const float bfv[4] = {bF.x, bF.y, bF.z, bF.w};                             \
    const float biv[4] = {bI.x, bI.y, bI.z, bI.w};                             \
    const float bgv[4] = {bG.x, bG.y, bG.z, bG.w};                             \
    const float bov[4] = {bO.x, bO.y, bO.z, bO.w};                             \
    _Pragma("unroll") for (int r = 0; r < 4; ++r) {                            \
      float fg = 1.f / (1.f + __expf(-(acc[0][r] + bfv[r])));                  \
      float ig = 1.f / (1.f + __expf(-(acc[1][r] + biv[r])));                  \
      float e2 = __expf(2.f * (acc[2][r] + bgv[r]));                           \
      float gg = (e2 - 1.f) / (e2 + 1.f);                                      \
      float og = 1.f / (1.f + __expf(-(acc[3][r] + bov[r])));                  \
      float cn = fg * cst[r] + ig * gg;                                        \
      cst[r] = cn;                                                             \
      float e2c = __expf(2.f * cn);                                            \
      hv[r] = og * (e2c - 1.f) / (e2c + 1.f);                                  \
    }                                                                          \
  }

  if (!isL1) {
    // ================= layer 0 =================
    bf16x8 xr[8];
    {
      const unsigned short* xp = xseq + (size_t)batch * kE + g4 * 8;  // t=0
#pragma unroll
      for (int kc = 0; kc < 8; ++kc) xr[kc] = *(const bf16x8*)(xp + kc * 32);
    }
    for (int t = 0; t < kT; ++t) {
      pollgate(pollp, t - throff);  // also drains xr prefetch (vmcnt 0)
      bf16x8 vF[16];
      issue16_sc1(hbuf + (size_t)((t + 7) & 7) * kBH + batch * kH + g4 * 8, vF);
      f32x4 acc[4] = {{0, 0, 0, 0}, {0, 0, 0, 0}, {0, 0, 0, 0}, {0, 0, 0, 0}};
#pragma unroll
      for (int kc = 0; kc < 8; ++kc) MFMA_KC(kc, xr[kc])  // U-part; vF in flight
      wait4_vm12(vF);
#pragma unroll
      for (int kc = 0; kc < 4; ++kc) MFMA_KC(8 + kc, vF[kc])
      wait4_vm8(vF + 4);
#pragma unroll
      for (int kc = 4; kc < 8; ++kc) MFMA_KC(8 + kc, vF[kc])
      wait4_vm4(vF + 8);
#pragma unroll
      for (int kc = 8; kc < 12; ++kc) MFMA_KC(8 + kc, vF[kc])
      wait4_vm0(vF + 12);
#pragma unroll
      for (int kc = 12; kc < 16; ++kc) MFMA_KC(8 + kc, vF[kc])
      GATE_EPILOGUE(hv)
      unsigned int lo = (unsigned)f2bf(hv[0]) | ((unsigned)f2bf(hv[1]) << 16);
      unsigned int hi = (unsigned)f2bf(hv[2]) | ((unsigned)f2bf(hv[3]) << 16);
      int32x2 pk = {(int)lo, (int)hi};
      store_dwordx2_sc1(hbuf + (size_t)(t & 7) * kBH + batch * kH + hid4, pk);
      if (t + 1 < kT) {  // prefetch next x; stays in flight across flag store
        const unsigned short* xp =
            xseq + ((size_t)(t + 1) * kB + batch) * kE + g4 * 8;
#pragma unroll
        for (int kc = 0; kc < 8; ++kc) xr[kc] = *(const bf16x8*)(xp + kc * 32);
        asm volatile("s_waitcnt vmcnt(8)" ::: "memory");  // h-store acked only
      } else {
        asm volatile("s_waitcnt vmcnt(0)" ::: "memory");
      }
      if (lane == 0) store_int_sc1(myflag, t + 1);
    }
  } else {
    // ================= layer 1 =================
    for (int s = 0; s < kT; ++s) {
      pollgate(pollp, s - throff);
      bf16x8 uF[16], vF[16];
      issue16_sc1(hbuf + (size_t)(s & 7) * kBH + batch * kH + g4 * 8, uF);
      issue16_sc1(h1buf + (size_t)((s + 1) & 1) * kBH + batch * kH + g4 * 8, vF);
      f32x4 acc[4] = {{0, 0, 0, 0}, {0, 0, 0, 0}, {0, 0, 0, 0}, {0, 0, 0, 0}};
      wait8_vm24(uF);       // oldest 8 (uF[0..7]) complete
#pragma unroll
      for (int kc = 0; kc < 8; ++kc) MFMA_KC(kc, uF[kc])
      wait8_vm16(uF + 8);   // uF[8..15]
#pragma unroll
      for (int kc = 8; kc < 16; ++kc) MFMA_KC(kc, uF[kc])
      wait8_vm8(vF);        // vF[0..7]
#pragma unroll
      for (int kc = 0; kc < 8; ++kc) MFMA_KC(16 + kc, vF[kc])
      wait8_vm0(vF + 8);    // vF[8..15]
#pragma unroll
      for (int kc = 8; kc < 16; ++kc) MFMA_KC(16 + kc, vF[kc])
      GATE_EPILOGUE(hv)
      if (s == kT - 1) {
        f32x4 hq = {hv[0], hv[1], hv[2], hv[3]};
        *(f32x4*)(h1f + (size_t)batch * kH + hid4) = hq;  // kernel-end flush
      } else {
        unsigned int lo = (unsigned)f2bf(hv[0]) | ((unsigned)f2bf(hv[1]) << 16);
        unsigned int hi = (unsigned)f2bf(hv[2]) | ((unsigned)f2bf(hv[3]) << 16);
        int32x2 pk = {(int)lo, (int)hi};
        store_dwordx2_sc1(h1buf + (size_t)(s & 1) * kBH + batch * kH + hid4, pk);
      }
      asm volatile("s_waitcnt vmcnt(0)" ::: "memory");
      if (lane == 0) store_int_sc1(myflag, s + 1);
    }
  }
#undef GATE_EPILOGUE
#undef MFMA_KC
}

// out[b][v] = 2*sum_k h1[b][k]*Wout[k][v] + bout[v]; 32 batches per block
// (R14-proven: 250 blocks, 64KB LDS, 2 WG/CU — parallelism beats the 2x
// W_out re-read; the 125-block single-pass variant regressed ~140us)
__global__ void head(const float* __restrict__ h1f, const float* __restrict__ Wout,
                     const float* __restrict__ bout, float* __restrict__ out) {
  extern __shared__ float hs[];  // [32][512]
  const int v = blockIdx.x * 256 + threadIdx.x;
  const int half = blockIdx.y;
  for (int i = threadIdx.x; i < 32 * kH; i += 256) hs[i] = h1f[half * 32 * kH + i];
  __syncthreads();
  float acc[32];
#pragma unroll
  for (int r = 0; r < 32; ++r) acc[r] = 0.f;
  for (int k = 0; k < kH; k += 4) {
    float w0 = Wout[(size_t)k * kV + v];
    float w1 = Wout[(size_t)(k + 1) * kV + v];
    float w2 = Wout[(size_t)(k + 2) * kV + v];
    float w3 = Wout[(size_t)(k + 3) * kV + v];
#pragma unroll
    for (int r = 0; r < 32; ++r) {
      float4 h4 = *(const float4*)&hs[r * kH + k];
      acc[r] += h4.x * w0 + h4.y * w1 + h4.z * w2 + h4.w * w3;
    }
  }
  float bv = bout[v];
#pragma unroll
  for (int r = 0; r < 32; ++r)
    out[(size_t)(half * 32 + r) * kV + v] = 2.f * acc[r] + bv;
}

extern "C" void kernel_launch(void* const* d_in, const int* in_sizes, int n_in,
                              void* d_out, int out_size, void* d_ws, size_t ws_size,
                              hipStream_t stream) {
  const int*   X     = (const int*)d_in[0];
  const float* emb   = (const float*)d_in[1];
  const float* U_f   = (const float*)d_in[2];
  const float* V_f   = (const float*)d_in[3];
  const float* b_f   = (const float*)d_in[4];
  const float* U_i   = (const float*)d_in[5];
  const float* V_i   = (const float*)d_in[6];
  const float* b_i   = (const float*)d_in[7];
  const float* U_g   = (const float*)d_in[8];
  const float* V_g   = (const float*)d_in[9];
  const float* b_g   = (const float*)d_in[10];
  const float* U_o   = (const float*)d_in[11];
  const float* U_f1  = (const float*)d_in[12];
  const float* V_f1  = (const float*)d_in[13];
  const float* b_f1  = (const float*)d_in[14];
  const float* U_i1  = (const float*)d_in[15];
  const float* V_i1  = (const float*)d_in[16];
  const float* b_i1  = (const float*)d_in[17];
  const float* U_g1  = (const float*)d_in[18];
  const float* V_g1  = (const float*)d_in[19];
  const float* b_g1  = (const float*)d_in[20];
  const float* U_o1  = (const float*)d_in[21];
  const float* V_o1  = (const float*)d_in[22];
  const float* b_o1  = (const float*)d_in[23];
  const float* W_out = (const float*)d_in[24];
  const float* b_out = (const float*)d_in[25];

  char* ws = (char*)d_ws;
  auto alloc = [&](size_t bytes) -> char* {
    char* p = ws;
    ws += (bytes + 255) & ~(size_t)255;
    return p;
  };
  unsigned short* U0p   = (unsigned short*)alloc((size_t)kE * 2048 * 2);
  unsigned short* V0p   = (unsigned short*)alloc((size_t)kH * 2048 * 2);
  unsigned short* U1p   = (unsigned short*)alloc((size_t)kH * 2048 * 2);
  unsigned short* V1p   = (unsigned short*)alloc((size_t)kH * 2048 * 2);
  unsigned short* xseq  = (unsigned short*)alloc((size_t)kT * kB * kE * 2);
  unsigned short* hbuf  = (unsigned short*)alloc((size_t)8 * kBH * 2);
  unsigned short* h1buf = (unsigned short*)alloc((size_t)2 * kBH * 2);
  float* h1f   = (float*)alloc((size_t)kBH * 4);
  float* bcat0 = (float*)alloc(4 * 512 * 4);
  float* bcat1 = (float*)alloc(4 * 512 * 4);
  int* fl0     = (int*)alloc(4 * 32 * FSTR * 4);
  int* fl1     = (int*)alloc(4 * 32 * FSTR * 4);

  // fused weight packing (layer0 o-gate uses V_o1 and b_o1 — reference quirk)
  pack_all<<<dim3((kH * 2048 + 255) / 256, 4), 256, 0, stream>>>(
      U_f, U_i, U_g, U_o, V_f, V_i, V_g, V_o1,
      U_f1, U_i1, U_g1, U_o1, V_f1, V_i1, V_g1,
      U0p, V0p, U1p, V1p);
  gather_x<<<(kT * kB * (kE / 8) + 255) / 256, 256, 0, stream>>>(X, emb, xseq);
  init_state<<<(8 * kBH + 255) / 256, 256, 0, stream>>>(
      hbuf, h1buf, bcat0, bcat1, fl0, fl1,
      b_f, b_i, b_g, b_o1, b_f1, b_i1, b_g1);

  (void)hipFuncSetAttribute((const void*)lstm_rec,
                            hipFuncAttributeMaxDynamicSharedMemorySize, 131072);
  void* args[] = {
      (void*)&xseq, (void*)&U0p, (void*)&V0p, (void*)&U1p, (void*)&V1p,
      (void*)&bcat0, (void*)&bcat1, (void*)&hbuf, (void*)&h1buf,
      (void*)&h1f, (void*)&fl0, (void*)&fl1};
  (void)hipLaunchCooperativeKernel((const void*)lstm_rec, dim3(256), dim3(64),
                                   args, 131072, stream);

  head<<<dim3(kV / 256, 2), 256, 65536, stream>>>(h1f, W_out, b_out,
                                                  (float*)d_out);
}

// Round 18
// 2350.882 us; speedup vs baseline: 1.0675x; 1.0085x over previous
//
#include <hip/hip_runtime.h>
#include <hip/hip_bf16.h>

typedef __attribute__((ext_vector_type(8))) short bf16x8;
typedef __attribute__((ext_vector_type(4))) float f32x4;
typedef __attribute__((ext_vector_type(2))) int int32x2;

constexpr int kB = 64;      // batch
constexpr int kT = 512;     // time steps
constexpr int kE = 256;     // embedding
constexpr int kH = 512;     // hidden
constexpr int kV = 32000;   // vocab
constexpr int kBH = kB * kH;
constexpr int FSTR = 16;    // flag stride (ints) = 64B padding

static __device__ __forceinline__ unsigned short f2bf(float x) {
  __hip_bfloat16 h = __float2bfloat16(x);
  return __builtin_bit_cast(unsigned short, h);
}

static __device__ __forceinline__ f32x4 mfma16(bf16x8 a, bf16x8 b, f32x4 c) {
  return __builtin_amdgcn_mfma_f32_16x16x32_bf16(a, b, c, 0, 0, 0);
}

// issue 16 dwordx4 sc1 loads (64B stride), NO wait — overlap with compute.
static __device__ __forceinline__ void issue16_sc1(const unsigned short* p, bf16x8* a) {
  asm volatile(
      "global_load_dwordx4 %0, %16, off sc1\n\t"
      "global_load_dwordx4 %1, %16, off offset:64 sc1\n\t"
      "global_load_dwordx4 %2, %16, off offset:128 sc1\n\t"
      "global_load_dwordx4 %3, %16, off offset:192 sc1\n\t"
      "global_load_dwordx4 %4, %16, off offset:256 sc1\n\t"
      "global_load_dwordx4 %5, %16, off offset:320 sc1\n\t"
      "global_load_dwordx4 %6, %16, off offset:384 sc1\n\t"
      "global_load_dwordx4 %7, %16, off offset:448 sc1\n\t"
      "global_load_dwordx4 %8, %16, off offset:512 sc1\n\t"
      "global_load_dwordx4 %9, %16, off offset:576 sc1\n\t"
      "global_load_dwordx4 %10, %16, off offset:640 sc1\n\t"
      "global_load_dwordx4 %11, %16, off offset:704 sc1\n\t"
      "global_load_dwordx4 %12, %16, off offset:768 sc1\n\t"
      "global_load_dwordx4 %13, %16, off offset:832 sc1\n\t"
      "global_load_dwordx4 %14, %16, off offset:896 sc1\n\t"
      "global_load_dwordx4 %15, %16, off offset:960 sc1"
      : "=&v"(a[0]), "=&v"(a[1]), "=&v"(a[2]), "=&v"(a[3]),
        "=&v"(a[4]), "=&v"(a[5]), "=&v"(a[6]), "=&v"(a[7]),
        "=&v"(a[8]), "=&v"(a[9]), "=&v"(a[10]), "=&v"(a[11]),
        "=&v"(a[12]), "=&v"(a[13]), "=&v"(a[14]), "=&v"(a[15])
      : "v"(p));
}

// tied waits on 4 frags with various residual counts (straight-line use only;
// NEVER carry asm-load dests across a loop backedge — R15 NaN lesson)
#define WAIT4(NAME, CNT)                                                    \
  static __device__ __forceinline__ void NAME(bf16x8* a) {                  \
    asm volatile("s_waitcnt vmcnt(" #CNT ")"                                \
                 : "+v"(a[0]), "+v"(a[1]), "+v"(a[2]), "+v"(a[3])           \
                 :                                                          \
                 : "memory");                                               \
  }
WAIT4(wait4_vm12, 12)
WAIT4(wait4_vm8, 8)
WAIT4(wait4_vm4, 4)
WAIT4(wait4_vm0, 0)
#undef WAIT4

#define WAIT8(NAME, CNT)                                                    \
  static __device__ __forceinline__ void NAME(bf16x8* a) {                  \
    asm volatile("s_waitcnt vmcnt(" #CNT ")"                                \
                 : "+v"(a[0]), "+v"(a[1]), "+v"(a[2]), "+v"(a[3]),          \
                   "+v"(a[4]), "+v"(a[5]), "+v"(a[6]), "+v"(a[7])           \
                 :                                                          \
                 : "memory");                                               \
  }
WAIT8(wait8_vm8, 8)
WAIT8(wait8_vm0, 0)
#undef WAIT8

// tied vmcnt(16) on 16 frags: no stall when exactly 16 loads outstanding,
// but provides the data-dep (rule #18) ordering MFMAs after this point.
static __device__ __forceinline__ void tie16_vm16(bf16x8* a) {
  asm volatile("s_waitcnt vmcnt(16)"
               : "+v"(a[0]), "+v"(a[1]), "+v"(a[2]), "+v"(a[3]),
                 "+v"(a[4]), "+v"(a[5]), "+v"(a[6]), "+v"(a[7]),
                 "+v"(a[8]), "+v"(a[9]), "+v"(a[10]), "+v"(a[11]),
                 "+v"(a[12]), "+v"(a[13]), "+v"(a[14]), "+v"(a[15])
               :
               : "memory");
}

static __device__ __forceinline__ void store_dwordx2_sc1(unsigned short* p, int32x2 v) {
  asm volatile("global_store_dwordx2 %0, %1, off sc1" ::"v"(p), "v"(v) : "memory");
}

static __device__ __forceinline__ void store_int_sc1(int* p, int v) {
  asm volatile("global_store_dword %0, %1, off sc1" ::"v"(p), "v"(v) : "memory");
}

// spin until (per-lane) *p >= thr for all 64 lanes; 1 dword sc1 load/lane/iter.
static __device__ __forceinline__ void pollgate(const int* p, int thr) {
  while (true) {
    int v;
    asm volatile("global_load_dword %0, %1, off sc1\n\ts_waitcnt vmcnt(0)"
                 : "=&v"(v)
                 : "v"(p)
                 : "memory");
    if (__all(v >= thr)) break;
  }
}

// Pack weights into A-fragment slices: P[hb][kc][gate][lane][j]
//   = src_gate[(kc*32 + (lane>>4)*8 + j) * kH + hb*16 + (lane&15)]
// blockIdx.y selects which of the 4 packed matrices (fused single launch).
__global__ void pack_all(const float* __restrict__ U_f, const float* __restrict__ U_i,
                         const float* __restrict__ U_g, const float* __restrict__ U_o,
                         const float* __restrict__ V_f, const float* __restrict__ V_i,
                         const float* __restrict__ V_g, const float* __restrict__ V_o1,
                         const float* __restrict__ U_f1, const float* __restrict__ U_i1,
                         const float* __restrict__ U_g1, const float* __restrict__ U_o1,
                         const float* __restrict__ V_f1, const float* __restrict__ V_i1,
                         const float* __restrict__ V_g1,
                         unsigned short* __restrict__ U0p, unsigned short* __restrict__ V0p,
                         unsigned short* __restrict__ U1p, unsigned short* __restrict__ V1p) {
  const int which = blockIdx.y;
  const float *s0, *s1, *s2, *s3;
  unsigned short* dst;
  int K;
  if (which == 0)      { s0 = U_f;  s1 = U_i;  s2 = U_g;  s3 = U_o;  dst = U0p; K = kE; }
  else if (which == 1) { s0 = V_f;  s1 = V_i;  s2 = V_g;  s3 = V_o1; dst = V0p; K = kH; }
  else if (which == 2) { s0 = U_f1; s1 = U_i1; s2 = U_g1; s3 = U_o1; dst = U1p; K = kH; }
  else                 { s0 = V_f1; s1 = V_i1; s2 = V_g1; s3 = V_o1; dst = V1p; K = kH; }
  int o = blockIdx.x * 256 + threadIdx.x;
  if (o >= K * 2048) return;
  int j = o & 7;
  int lane = (o >> 3) & 63;
  int gate = (o >> 9) & 3;
  int r2 = o >> 11;
  int kc = r2 % (K / 32);
  int hb = r2 / (K / 32);
  int k = kc * 32 + (lane >> 4) * 8 + j;
  int hid = hb * 16 + (lane & 15);
  const float* s = (gate == 0) ? s0 : (gate == 1) ? s1 : (gate == 2) ? s2 : s3;
  dst[o] = f2bf(s[(size_t)k * kH + hid]);
}

// xseq[t][b][e] = bf16(emb[X[b][t]][e])
__global__ void gather_x(const int* __restrict__ X, const float* __restrict__ emb,
                         unsigned short* __restrict__ xseq) {
  int o = blockIdx.x * 256 + threadIdx.x;
  if (o >= kT * kB * (kE / 8)) return;
  int e8 = o & 31;
  int b = (o >> 5) & 63;
  int t = o >> 11;
  int tok = X[b * kT + t];
  const float* src = emb + (size_t)tok * kE + e8 * 8;
  unsigned short tmp[8];
#pragma unroll
  for (int j = 0; j < 8; ++j) tmp[j] = f2bf(src[j]);
  unsigned short* dst = xseq + ((size_t)t * kB + b) * kE + e8 * 8;
#pragma unroll
  for (int j = 0; j < 8; ++j) dst[j] = tmp[j];
}

// init states to ones; planar bias arrays [4][512]; zero flags
__global__ void init_state(unsigned short* hbuf, unsigned short* h1buf,
                           float* bcat0, float* bcat1, int* fl0, int* fl1,
                           const float* b_f, const float* b_i, const float* b_g,
                           const float* b_o1,
                           const float* b_f1, const float* b_i1, const float* b_g1) {
  int i = blockIdx.x * 256 + threadIdx.x;
  if (i < 8 * kBH) hbuf[i] = 0x3F80u;  // bf16 1.0
  if (i < 2 * kBH) h1buf[i] = 0x3F80u;
  if (i < 512) {
    bcat0[i] = b_f[i];  bcat0[512 + i] = b_i[i];
    bcat0[1024 + i] = b_g[i];  bcat0[1536 + i] = b_o1[i];
    bcat1[i] = b_f1[i]; bcat1[512 + i] = b_i1[i];
    bcat1[1024 + i] = b_g1[i]; bcat1[1536 + i] = b_o1[i];
  }
  if (i < 4 * 32 * FSTR) { fl0[i] = 0; fl1[i] = 0; }
}

// Persistent recurrence: 256 WGs x 64 threads (1 wave each, 1 per CU).
// WGs [0,128): layer0 (h).  WGs [128,256): layer1 (h1).
// wl = wg&127; hb = wl>>2 (hidden block), bt = wl&3 (batch group of 16).
// Point-to-point flags along true dependencies, per bt-group (R6-proven):
//   L0 step t: fl0[bt][*] >= t (vF = h(t-1)); fl1[bt][*] >= t-7 (slot reuse)
//   L1 step s: fl0[bt][*] >= s+1 (uF = h(s)); fl1[bt][*] >= s (vF = h1(s-1))
// R18: L1 SPLIT-POLL — spin fl0 first (usually satisfied; L0 runs ahead),
// issue uF, then spin fl1 (the pacer) while uF flies. Hides the uF RTT.
__global__ void __launch_bounds__(64, 1)
lstm_rec(const unsigned short* __restrict__ xseq,
         const unsigned short* __restrict__ U0p, const unsigned short* __restrict__ V0p,
         const unsigned short* __restrict__ U1p, const unsigned short* __restrict__ V1p,
         const float* __restrict__ bcat0, const float* __restrict__ bcat1,
         unsigned short* __restrict__ hbuf,   // [8][64][512] bf16
         unsigned short* __restrict__ h1buf,  // [2][64][512] bf16
         float* __restrict__ h1f,             // [64][512] fp32 final h1
         int* __restrict__ fl0,               // [4][32*FSTR] L0 flags
         int* __restrict__ fl1)               // [4][32*FSTR] L1 flags
{
  extern __shared__ unsigned short lds[];
  const int lane = threadIdx.x;
  const int wg = blockIdx.x;
  const bool isL1 = wg >= 128;
  const int wl = wg & 127;
  const int hb = wl >> 2, bt = wl & 3;
  const int l15 = lane & 15, g4 = lane >> 4;
  const int batch = bt * 16 + l15;
  const int hid4 = hb * 16 + g4 * 4;
  const int KU = isL1 ? 512 : 256;

  // stage this WG's weight slice (A-fragment layout) into LDS, once
  {
    const unsigned short* Wu = isL1 ? U1p : U0p;
    const unsigned short* Wv = isL1 ? V1p : V0p;
    const int nu = KU * 64, nv = 512 * 64;
    const bf16x8* su = (const bf16x8*)(Wu + (size_t)hb * nu);
    bf16x8* d = (bf16x8*)lds;
    for (int i = lane; i < nu / 8; i += 64) d[i] = su[i];
    const bf16x8* sv = (const bf16x8*)(Wv + (size_t)hb * nv);
    bf16x8* d2 = (bf16x8*)(lds + nu);
    for (int i = lane; i < nv / 8; i += 64) d2[i] = sv[i];
  }

  // poll pointers: all-lanes fl0 view and all-lanes fl1 view
  const int* f0p = fl0 + bt * 32 * FSTR + (lane & 31) * FSTR;
  const int* f1p = fl1 + bt * 32 * FSTR + (lane & 31) * FSTR;
  // L0 combined poll (R6 scheme): lanes<32 watch fl0, lanes>=32 watch fl1
  const int* pollp = (lane < 32) ? f0p : (fl1 + bt * 32 * FSTR + (lane - 32) * FSTR);
  const int throffL0 = (lane < 32) ? 0 : 7;
  int* myflag = (isL1 ? fl1 : fl0) + bt * 32 * FSTR + hb * FSTR;

  const float* bc = isL1 ? bcat1 : bcat0;
  const float4 bF = *(const float4*)(bc + 0 * 512 + hid4);
  const float4 bI = *(const float4*)(bc + 1 * 512 + hid4);
  const float4 bG = *(const float4*)(bc + 2 * 512 + hid4);
  const float4 bO = *(const float4*)(bc + 3 * 512 + hid4);
  float cst[4] = {1.f, 1.f, 1.f, 1.f};

#define MFMA_KC(BASE_KC, FRAG)                                               \
  {                                                                          \
    const unsigned short* ab = lds + (BASE_KC) * 2048 + lane * 8;            \
    acc[0] = mfma16(*(const bf16x8*)ab, FRAG, acc[0]);                       \
    acc[1] = mfma16(*(const bf16x8*)(ab + 512), FRAG, acc[1]);               \
    acc[2] = mfma16(*(const bf16x8*)(ab + 1024), FRAG, acc[2]);              \
    acc[3] = mfma16(*(const bf16x8*)(ab + 1536), FRAG, acc[3]);              \
  }

#define GATE_EPILOGUE(hv)                                                      \
  float hv[4];                                                                 \
  {                                                                            \
    const float bfv[4] = {bF.x, bF.y, bF.z, bF.w};                             \
    const float biv[4] = {bI.x, bI.y, bI.z, bI.w};                             \
    const float bgv[4] = {bG.x, bG.y, bG.z, bG.w};                             \
    const float bov[4] = {bO.x, bO.y, bO.z, bO.w};                             \
    _Pragma("unroll") for (int r = 0; r < 4; ++r) {                            \
      float fg = 1.f / (1.f + __expf(-(acc[0][r] + bfv[r])));                  \
      float ig = 1.f / (1.f + __expf(-(acc[1][r] + biv[r])));                  \
      float e2 = __expf(2.f * (acc[2][r] + bgv[r]));                           \
      float gg = (e2 - 1.f) / (e2 + 1.f);                                      \
      float og = 1.f / (1.f + __expf(-(acc[3][r] + bov[r])));                  \
      float cn = fg * cst[r] + ig * gg;                                        \
      cst[r] = cn;                                                             \
      float e2c = __expf(2.f * cn);                                            \
      hv[r] = og * (e2c - 1.f) / (e2c + 1.f);                                  \
    }                                                                          \
  }

  if (!isL1) {
    // ================= layer 0 =================
    bf16x8 xr[8];
    {
      const unsigned short* xp = xseq + (size_t)batch * kE + g4 * 8;  // t=0
#pragma unroll
      for (int kc = 0; kc < 8; ++kc) xr[kc] = *(const bf16x8*)(xp + kc * 32);
    }
    for (int t = 0; t < kT; ++t) {
      pollgate(pollp, t - throffL0);  // fl0>=t & fl1>=t-7; drains xr prefetch
      bf16x8 vF[16];
      issue16_sc1(hbuf + (size_t)((t + 7) & 7) * kBH + batch * kH + g4 * 8, vF);
      f32x4 acc[4] = {{0, 0, 0, 0}, {0, 0, 0, 0}, {0, 0, 0, 0}, {0, 0, 0, 0}};
#pragma unroll
      for (int kc = 0; kc < 8; ++kc) MFMA_KC(kc, xr[kc])  // U-part; vF in flight
      wait4_vm12(vF);
#pragma unroll
      for (int kc = 0; kc < 4; ++kc) MFMA_KC(8 + kc, vF[kc])
      wait4_vm8(vF + 4);
#pragma unroll
      for (int kc = 4; kc < 8; ++kc) MFMA_KC(8 + kc, vF[kc])
      wait4_vm4(vF + 8);
#pragma unroll
      for (int kc = 8; kc < 12; ++kc) MFMA_KC(8 + kc, vF[kc])
      wait4_vm0(vF + 12);
#pragma unroll
      for (int kc = 12; kc < 16; ++kc) MFMA_KC(8 + kc, vF[kc])
      GATE_EPILOGUE(hv)
      unsigned int lo = (unsigned)f2bf(hv[0]) | ((unsigned)f2bf(hv[1]) << 16);
      unsigned int hi = (unsigned)f2bf(hv[2]) | ((unsigned)f2bf(hv[3]) << 16);
      int32x2 pk = {(int)lo, (int)hi};
      store_dwordx2_sc1(hbuf + (size_t)(t & 7) * kBH + batch * kH + hid4, pk);
      if (t + 1 < kT) {  // prefetch next x; stays in flight across flag store
        const unsigned short* xp =
            xseq + ((size_t)(t + 1) * kB + batch) * kE + g4 * 8;
#pragma unroll
        for (int kc = 0; kc < 8; ++kc) xr[kc] = *(const bf16x8*)(xp + kc * 32);
        asm volatile("s_waitcnt vmcnt(8)" ::: "memory");  // h-store acked only
      } else {
        asm volatile("s_waitcnt vmcnt(0)" ::: "memory");
      }
      if (lane == 0) store_int_sc1(myflag, t + 1);
    }
  } else {
    // ================= layer 1 (split-poll) =================
    for (int s = 0; s < kT; ++s) {
      // 1) uF readiness: fl0 >= s+1 (L0 runs ahead -> usually no spin)
      pollgate(f0p, s + 1);
      bf16x8 uF[16], vF[16];
      issue16_sc1(hbuf + (size_t)(s & 7) * kBH + batch * kH + g4 * 8, uF);
      // 2) the real pacer: fl1 >= s; uF flies during this spin (each poll
      //    iteration drains vmcnt, so uF is in-regs when the spin exits)
      pollgate(f1p, s);
      issue16_sc1(h1buf + (size_t)((s + 1) & 1) * kBH + batch * kH + g4 * 8, vF);
      tie16_vm16(uF);  // no stall (16 vF outstanding); rule-#18 ordering
      f32x4 acc[4] = {{0, 0, 0, 0}, {0, 0, 0, 0}, {0, 0, 0, 0}, {0, 0, 0, 0}};
#pragma unroll
      for (int kc = 0; kc < 16; ++kc) MFMA_KC(kc, uF[kc])  // U-part || vF RTT
      wait8_vm8(vF);        // vF[0..7]
#pragma unroll
      for (int kc = 0; kc < 8; ++kc) MFMA_KC(16 + kc, vF[kc])
      wait8_vm0(vF + 8);    // vF[8..15]
#pragma unroll
      for (int kc = 8; kc < 16; ++kc) MFMA_KC(16 + kc, vF[kc])
      GATE_EPILOGUE(hv)
      if (s == kT - 1) {
        f32x4 hq = {hv[0], hv[1], hv[2], hv[3]};
        *(f32x4*)(h1f + (size_t)batch * kH + hid4) = hq;  // kernel-end flush
      } else {
        unsigned int lo = (unsigned)f2bf(hv[0]) | ((unsigned)f2bf(hv[1]) << 16);
        unsigned int hi = (unsigned)f2bf(hv[2]) | ((unsigned)f2bf(hv[3]) << 16);
        int32x2 pk = {(int)lo, (int)hi};
        store_dwordx2_sc1(h1buf + (size_t)(s & 1) * kBH + batch * kH + hid4, pk);
      }
      asm volatile("s_waitcnt vmcnt(0)" ::: "memory");  // ack h1 store
      if (lane == 0) store_int_sc1(myflag, s + 1);
    }
  }
#undef GATE_EPILOGUE
#undef MFMA_KC
}

// out[b][v] = 2*sum_k h1[b][k]*Wout[k][v] + bout[v]; 32 batches per block
// (R14-proven: 250 blocks, 64KB LDS, 2 WG/CU — parallelism beats the 2x
// W_out re-read; the 125-block single-pass variant regressed ~140us)
__global__ void head(const float* __restrict__ h1f, const float* __restrict__ Wout,
                     const float* __restrict__ bout, float* __restrict__ out) {
  extern __shared__ float hs[];  // [32][512]
  const int v = blockIdx.x * 256 + threadIdx.x;
  const int half = blockIdx.y;
  for (int i = threadIdx.x; i < 32 * kH; i += 256) hs[i] = h1f[half * 32 * kH + i];
  __syncthreads();
  float acc[32];
#pragma unroll
  for (int r = 0; r < 32; ++r) acc[r] = 0.f;
  for (int k = 0; k < kH; k += 4) {
    float w0 = Wout[(size_t)k * kV + v];
    float w1 = Wout[(size_t)(k + 1) * kV + v];
    float w2 = Wout[(size_t)(k + 2) * kV + v];
    float w3 = Wout[(size_t)(k + 3) * kV + v];
#pragma unroll
    for (int r = 0; r < 32; ++r) {
      float4 h4 = *(const float4*)&hs[r * kH + k];
      acc[r] += h4.x * w0 + h4.y * w1 + h4.z * w2 + h4.w * w3;
    }
  }
  float bv = bout[v];
#pragma unroll
  for (int r = 0; r < 32; ++r)
    out[(size_t)(half * 32 + r) * kV + v] = 2.f * acc[r] + bv;
}

extern "C" void kernel_launch(void* const* d_in, const int* in_sizes, int n_in,
                              void* d_out, int out_size, void* d_ws, size_t ws_size,
                              hipStream_t stream) {
  const int*   X     = (const int*)d_in[0];
  const float* emb   = (const float*)d_in[1];
  const float* U_f   = (const float*)d_in[2];
  const float* V_f   = (const float*)d_in[3];
  const float* b_f   = (const float*)d_in[4];
  const float* U_i   = (const float*)d_in[5];
  const float* V_i   = (const float*)d_in[6];
  const float* b_i   = (const float*)d_in[7];
  const float* U_g   = (const float*)d_in[8];
  const float* V_g   = (const float*)d_in[9];
  const float* b_g   = (const float*)d_in[10];
  const float* U_o   = (const float*)d_in[11];
  const float* U_f1  = (const float*)d_in[12];
  const float* V_f1  = (const float*)d_in[13];
  const float* b_f1  = (const float*)d_in[14];
  const float* U_i1  = (const float*)d_in[15];
  const float* V_i1  = (const float*)d_in[16];
  const float* b_i1  = (const float*)d_in[17];
  const float* U_g1  = (const float*)d_in[18];
  const float* V_g1  = (const float*)d_in[19];
  const float* b_g1  = (const float*)d_in[20];
  const float* U_o1  = (const float*)d_in[21];
  const float* V_o1  = (const float*)d_in[22];
  const float* b_o1  = (const float*)d_in[23];
  const float* W_out = (const float*)d_in[24];
  const float* b_out = (const float*)d_in[25];

  char* ws = (char*)d_ws;
  auto alloc = [&](size_t bytes) -> char* {
    char* p = ws;
    ws += (bytes + 255) & ~(size_t)255;
    return p;
  };
  unsigned short* U0p   = (unsigned short*)alloc((size_t)kE * 2048 * 2);
  unsigned short* V0p   = (unsigned short*)alloc((size_t)kH * 2048 * 2);
  unsigned short* U1p   = (unsigned short*)alloc((size_t)kH * 2048 * 2);
  unsigned short* V1p   = (unsigned short*)alloc((size_t)kH * 2048 * 2);
  unsigned short* xseq  = (unsigned short*)alloc((size_t)kT * kB * kE * 2);
  unsigned short* hbuf  = (unsigned short*)alloc((size_t)8 * kBH * 2);
  unsigned short* h1buf = (unsigned short*)alloc((size_t)2 * kBH * 2);
  float* h1f   = (float*)alloc((size_t)kBH * 4);
  float* bcat0 = (float*)alloc(4 * 512 * 4);
  float* bcat1 = (float*)alloc(4 * 512 * 4);
  int* fl0     = (int*)alloc(4 * 32 * FSTR * 4);
  int* fl1     = (int*)alloc(4 * 32 * FSTR * 4);

  // fused weight packing (layer0 o-gate uses V_o1 and b_o1 — reference quirk)
  pack_all<<<dim3((kH * 2048 + 255) / 256, 4), 256, 0, stream>>>(
      U_f, U_i, U_g, U_o, V_f, V_i, V_g, V_o1,
      U_f1, U_i1, U_g1, U_o1, V_f1, V_i1, V_g1,
      U0p, V0p, U1p, V1p);
  gather_x<<<(kT * kB * (kE / 8) + 255) / 256, 256, 0, stream>>>(X, emb, xseq);
  init_state<<<(8 * kBH + 255) / 256, 256, 0, stream>>>(
      hbuf, h1buf, bcat0, bcat1, fl0, fl1,
      b_f, b_i, b_g, b_o1, b_f1, b_i1, b_g1);

  (void)hipFuncSetAttribute((const void*)lstm_rec,
                            hipFuncAttributeMaxDynamicSharedMemorySize, 131072);
  void* args[] = {
      (void*)&xseq, (void*)&U0p, (void*)&V0p, (void*)&U1p, (void*)&V1p,
      (void*)&bcat0, (void*)&bcat1, (void*)&hbuf, (void*)&h1buf,
      (void*)&h1f, (void*)&fl0, (void*)&fl1};
  (void)hipLaunchCooperativeKernel((const void*)lstm_rec, dim3(256), dim3(64),
                                   args, 131072, stream);

  head<<<dim3(kV / 256, 2), 256, 65536, stream>>>(h1f, W_out, b_out,
                                                  (float*)d_out);
}